// Round 5
// baseline (100.080 us; speedup 1.0000x reference)
//
#include <hip/hip_runtime.h>
#include <cstdint>

// B=4, L=4096, D=3, VOCAB=8192
#define N_ROWS   16384
#define VOCAB    8192
#define NCHUNKS  512          // 16 codes per chunk
#define PCHUNKS  64           // LDS-staged prefix: 1024 codes

typedef unsigned long long u64;
typedef unsigned int u32;

// ws layout (bytes):
//   [0)      float4 sorted[8192]  (2e0,2e1,2e2,ee), approx-descending by ee
//   [131072) u32    order[8192]   original code index per sorted position
//   [163840) float  suf[513]      EXACT suffix-max of ee at chunk granularity
//   [167936) float  part[1024]    per-block loss partials
//   [172032) u32    counter       last-block-done counter
// d_out (floats): [0,49152) quant_ste | [49152,65536) idx | [65536] vq_loss

// ---------------------------------------------------------------------------
// Prep (1 block): bin-sort codes by ee descending (64 bins on float bits of
// ee), emit sorted float4 + order; build exact chunk suffix-max table.
// Sort quality only affects SPEED; correctness rests on suf[] being exact.
// ---------------------------------------------------------------------------
__global__ __launch_bounds__(1024) void vq_prep(
    const float* __restrict__ emb, float4* __restrict__ sorted,
    u32* __restrict__ order, float* __restrict__ suf, u32* __restrict__ counter)
{
    __shared__ u32 hist[64];
    __shared__ u32 starts[64];
    __shared__ int maxeb_s;
    __shared__ float cmax[512];

    const int t = threadIdx.x;
    if (t == 0) { maxeb_s = -1; counter[0] = 0u; }
    if (t < 64) hist[t] = 0u;
    __syncthreads();

    float e0[8], e1[8], e2[8], ee[8];
    int eb[8];
    int mymax = -1;
    #pragma unroll
    for (int i = 0; i < 8; ++i) {
        const int code = t + i * 1024;
        e0[i] = emb[3*code+0]; e1[i] = emb[3*code+1]; e2[i] = emb[3*code+2];
        ee[i] = __fadd_rn(__fadd_rn(__fmul_rn(e0[i],e0[i]), __fmul_rn(e1[i],e1[i])),
                          __fmul_rn(e2[i],e2[i]));          // frozen formula
        eb[i] = (int)(__float_as_uint(ee[i]) >> 22);        // monotonic in ee (ee>0)
        mymax = max(mymax, eb[i]);
    }
    atomicMax(&maxeb_s, mymax);
    __syncthreads();
    const int off = maxeb_s - 63;

    int sbin[8];
    #pragma unroll
    for (int i = 0; i < 8; ++i) {
        int b = eb[i] - off; b = b < 0 ? 0 : b;   // merged low bin (scanned last)
        sbin[i] = 63 - b;                          // 0 = largest ee
        atomicAdd(&hist[sbin[i]], 1u);
    }
    __syncthreads();
    if (t < 64) {                                  // exclusive prefix over bins
        const u32 h = hist[t];
        u32 incl = h;
        #pragma unroll
        for (int o = 1; o < 64; o <<= 1) {
            const u32 v = __shfl_up(incl, o, 64);
            if (t >= o) incl += v;
        }
        starts[t] = incl - h;
    }
    __syncthreads();
    #pragma unroll
    for (int i = 0; i < 8; ++i) {
        const u32 pos = atomicAdd(&starts[sbin[i]], 1u);
        sorted[pos] = make_float4(e0[i]+e0[i], e1[i]+e1[i], e2[i]+e2[i], ee[i]);
        order[pos]  = (u32)(t + i * 1024);
    }
    __syncthreads();

    // exact chunk maxima, then suffix-max (one wave, 8 chunks/lane)
    if (t < 512) {
        float m = sorted[t*16].w;
        #pragma unroll
        for (int i = 1; i < 16; ++i) m = fmaxf(m, sorted[t*16+i].w);
        cmax[t] = m;
    }
    __syncthreads();
    if (t < 64) {
        float v[8];
        #pragma unroll
        for (int i = 0; i < 8; ++i) v[i] = cmax[t*8+i];
        #pragma unroll
        for (int i = 6; i >= 0; --i) v[i] = fmaxf(v[i], v[i+1]);   // local suffix
        float incl = v[0];
        #pragma unroll
        for (int o = 1; o < 64; o <<= 1) {
            const float w = __shfl_down(incl, o, 64);
            if (t + o < 64) incl = fmaxf(incl, w);
        }
        float excl = __shfl_down(incl, 1, 64);
        if (t == 63) excl = 0.0f;
        #pragma unroll
        for (int i = 0; i < 8; ++i) suf[t*8+i] = fmaxf(v[i], excl);
        if (t == 0) suf[512] = 0.0f;
    }
}

// ---------------------------------------------------------------------------
// Main: 16 lanes per row, 4 rows per wave, 4 waves per block, 1024 blocks.
// Scan sorted codes; per-lane frozen distance; prune via exact suf[] bound.
// Typical row exits after ~4-8 chunks. Stragglers (tiny ||x||) fall through
// to a global 8-deep-batched loop. Tie-break = min original index (u64 key).
// ---------------------------------------------------------------------------
__global__ __launch_bounds__(256) void vq_main(
    const float* __restrict__ feats, const float* __restrict__ emb,
    const float4* __restrict__ sorted, const u32* __restrict__ order,
    const float* __restrict__ suf, float* __restrict__ out_quant,
    float* __restrict__ out_idx, float* __restrict__ part,
    u32* __restrict__ counter, float* __restrict__ loss_slot)
{
    __shared__ float4 sE[1024];
    __shared__ float  sSuf[513];
    __shared__ float  wsum[4];
    __shared__ int    winner;

    const int tid  = threadIdx.x;
    const int lane = tid & 63;
    const int wave = tid >> 6;
    const int c    = tid & 15;
    const int row  = blockIdx.x * 16 + (tid >> 4);

    sE[tid]       = sorted[tid];
    sE[tid + 256] = sorted[tid + 256];
    sE[tid + 512] = sorted[tid + 512];
    sE[tid + 768] = sorted[tid + 768];
    for (int i = tid; i < 513; i += 256) sSuf[i] = suf[i];

    const float x0 = feats[3*row+0];
    const float x1 = feats[3*row+1];
    const float x2 = feats[3*row+2];
    const float xx = __fadd_rn(__fadd_rn(__fmul_rn(x0,x0), __fmul_rn(x1,x1)),
                               __fmul_rn(x2,x2));
    const float sx = sqrtf(xx) - 1e-5f;   // conservative lower bound on ||x||

    __syncthreads();

    float best = __int_as_float(0x7f800000);
    int   bpos = c;
    bool  done = false;

    for (int k = 0; k < PCHUNKS; ++k) {
        const float4 E = sE[k*16 + c];
        const float xe2 = __fmaf_rn(x2, E.z, __fmaf_rn(x1, E.y, __fmul_rn(x0, E.x)));
        const float d   = __fadd_rn(__fsub_rn(xx, xe2), E.w);   // frozen (R4-validated)
        if (d < best) { best = d; bpos = k*16 + c; }
        if ((k & 3) == 3) {
            float gb = best;   // share row-best across the 16-lane group
            gb = fminf(gb, __shfl_xor(gb, 1, 64));
            gb = fminf(gb, __shfl_xor(gb, 2, 64));
            gb = fminf(gb, __shfl_xor(gb, 4, 64));
            gb = fminf(gb, __shfl_xor(gb, 8, 64));
            const float T  = sx - (sqrtf(gb + 1e-4f) + 1e-5f);
            const float T2 = (T > 0.0f) ? (T*T - 1e-5f) : -1.0e30f;
            if (__ballot(sSuf[k+1] >= T2) == 0ULL) { done = true; break; }
        }
    }

    if (!done) {   // rare straggler path: continue from global, 8 chunks in flight
        for (int kb = PCHUNKS; kb < NCHUNKS; kb += 8) {
            float4 Eb[8];
            #pragma unroll
            for (int j = 0; j < 8; ++j) Eb[j] = sorted[(kb+j)*16 + c];
            #pragma unroll
            for (int j = 0; j < 8; ++j) {
                const float4 E = Eb[j];
                const float xe2 = __fmaf_rn(x2, E.z, __fmaf_rn(x1, E.y, __fmul_rn(x0, E.x)));
                const float d   = __fadd_rn(__fsub_rn(xx, xe2), E.w);
                if (d < best) { best = d; bpos = (kb+j)*16 + c; }
            }
            if (kb + 8 >= NCHUNKS) break;
            float gb = best;
            gb = fminf(gb, __shfl_xor(gb, 1, 64));
            gb = fminf(gb, __shfl_xor(gb, 2, 64));
            gb = fminf(gb, __shfl_xor(gb, 4, 64));
            gb = fminf(gb, __shfl_xor(gb, 8, 64));
            const float T  = sx - (sqrtf(gb + 1e-4f) + 1e-5f);
            const float T2 = (T > 0.0f) ? (T*T - 1e-5f) : -1.0e30f;
            if (__ballot(sSuf[kb+8] >= T2) == 0ULL) break;
        }
    }

    // group argmin, np first-index tie-break via (d_bits, orig_idx) key
    const u32 orig = order[bpos];
    u64 key = ((u64)__float_as_uint(best) << 32) | (u64)orig;
    {
        u64 o;
        o = __shfl_xor(key, 1, 64); if (o < key) key = o;
        o = __shfl_xor(key, 2, 64); if (o < key) key = o;
        o = __shfl_xor(key, 4, 64); if (o < key) key = o;
        o = __shfl_xor(key, 8, 64); if (o < key) key = o;
    }

    float s = 0.0f;
    if (c == 0) {
        const u32 idx = (u32)(key & 0xffffffffULL);
        const float e0 = emb[3*idx+0];
        const float e1 = emb[3*idx+1];
        const float e2 = emb[3*idx+2];
        out_quant[3*row+0] = __fadd_rn(x0, __fsub_rn(e0, x0));
        out_quant[3*row+1] = __fadd_rn(x1, __fsub_rn(e1, x1));
        out_quant[3*row+2] = __fadd_rn(x2, __fsub_rn(e2, x2));
        out_idx[row] = (float)idx;
        const float d0 = e0 - x0, d1 = e1 - x1, d2 = e2 - x2;
        s = d0*d0 + d1*d1 + d2*d2;
    }
    #pragma unroll
    for (int o = 1; o < 64; o <<= 1) s += __shfl_xor(s, o, 64);
    if (lane == 0) wsum[wave] = s;
    __syncthreads();
    if (tid == 0) {
        part[blockIdx.x] = (wsum[0] + wsum[1]) + (wsum[2] + wsum[3]);
        __threadfence();
        const u32 old = atomicAdd(counter, 1u);
        winner = (old == 1023u) ? 1 : 0;
    }
    __syncthreads();
    if (winner) {   // deterministic final loss reduce by the last block
        float v = part[tid] + part[tid+256] + part[tid+512] + part[tid+768];
        #pragma unroll
        for (int o = 1; o < 64; o <<= 1) v += __shfl_xor(v, o, 64);
        if (lane == 0) wsum[wave] = v;
        __syncthreads();
        if (tid == 0) {
            const float S = (wsum[0] + wsum[1]) + (wsum[2] + wsum[3]);
            const float m = S / (float)(N_ROWS * 3);
            loss_slot[0] = __fadd_rn(m, __fmul_rn(0.25f, m));
        }
    }
}

extern "C" void kernel_launch(void* const* d_in, const int* in_sizes, int n_in,
                              void* d_out, int out_size, void* d_ws, size_t ws_size,
                              hipStream_t stream)
{
    const float* feats = (const float*)d_in[0];   // [4,4096,3] f32
    const float* emb   = (const float*)d_in[1];   // [8192,3]   f32
    float* out = (float*)d_out;

    char* ws = (char*)d_ws;
    float4* sorted  = (float4*)(ws);
    u32*    order   = (u32*)(ws + 131072);
    float*  suf     = (float*)(ws + 163840);
    float*  part    = (float*)(ws + 167936);
    u32*    counter = (u32*)(ws + 172032);

    vq_prep<<<1, 1024, 0, stream>>>(emb, sorted, order, suf, counter);
    vq_main<<<1024, 256, 0, stream>>>(feats, emb, sorted, order, suf,
                                      out, out + (size_t)N_ROWS * 3,
                                      part, counter, out + (size_t)N_ROWS * 4);
}